// Round 3
// baseline (30.507 us; speedup 1.0000x reference)
//
#include <hip/hip_runtime.h>

// CrossNet: x_{l+1} = x0 * (xl . w_l) + xl + b_l, 3 layers, fused.
// BATCH=16384, DIM=1024, LAYER_NUM=3. One 64-lane wave per row:
// each lane holds 16 elements (4x float4), dot via 6-step shfl_xor reduce.
// Memory-bound: read x once (64 MiB) + write out once (64 MiB).
// R2: nontemporal streaming loads/stores via ext_vector_type (HIP float4 is a
// class type that the nontemporal builtins reject).

#define CN_BATCH 16384
#define CN_DIM   1024
#define CN_LAYERS 3

typedef float f32x4 __attribute__((ext_vector_type(4)));

__global__ __launch_bounds__(256) void crossnet_kernel(
    const float* __restrict__ x,
    const float* __restrict__ kernels,
    const float* __restrict__ bias,
    float* __restrict__ out)
{
    const int wave = threadIdx.x >> 6;          // 0..3 (4 rows per block)
    const int lane = threadIdx.x & 63;
    const int row  = (blockIdx.x << 2) + wave;  // grid sized exactly: no bounds check

    const float* xrow = x + (size_t)row * CN_DIM;

    // Lane l covers elements {j*256 + l*4 .. +3} for j=0..3 (coalesced 16B).
    f32x4 x0[4], xl[4];
#pragma unroll
    for (int j = 0; j < 4; ++j) {
        x0[j] = __builtin_nontemporal_load(
                    reinterpret_cast<const f32x4*>(xrow + j * 256 + lane * 4));
        xl[j] = x0[j];
    }

#pragma unroll
    for (int i = 0; i < CN_LAYERS; ++i) {
        const float* krow = kernels + i * CN_DIM;
        const float* brow = bias    + i * CN_DIM;

        // Partial dot over this lane's 16 elements (k rows L1/L2-hot: keep cached).
        float partial = 0.0f;
#pragma unroll
        for (int j = 0; j < 4; ++j) {
            f32x4 k = *reinterpret_cast<const f32x4*>(krow + j * 256 + lane * 4);
            partial = fmaf(xl[j].x, k.x, partial);
            partial = fmaf(xl[j].y, k.y, partial);
            partial = fmaf(xl[j].z, k.z, partial);
            partial = fmaf(xl[j].w, k.w, partial);
        }
        // 64-lane butterfly reduce -> s broadcast to all lanes.
#pragma unroll
        for (int off = 32; off >= 1; off >>= 1)
            partial += __shfl_xor(partial, off, 64);
        const float s = partial;

        // xl = x0 * s + xl + bias_i
#pragma unroll
        for (int j = 0; j < 4; ++j) {
            f32x4 b = *reinterpret_cast<const f32x4*>(brow + j * 256 + lane * 4);
            xl[j].x = fmaf(x0[j].x, s, xl[j].x) + b.x;
            xl[j].y = fmaf(x0[j].y, s, xl[j].y) + b.y;
            xl[j].z = fmaf(x0[j].z, s, xl[j].z) + b.z;
            xl[j].w = fmaf(x0[j].w, s, xl[j].w) + b.w;
        }
    }

    float* orow = out + (size_t)row * CN_DIM;
#pragma unroll
    for (int j = 0; j < 4; ++j)
        __builtin_nontemporal_store(xl[j],
            reinterpret_cast<f32x4*>(orow + j * 256 + lane * 4));
}

extern "C" void kernel_launch(void* const* d_in, const int* in_sizes, int n_in,
                              void* d_out, int out_size, void* d_ws, size_t ws_size,
                              hipStream_t stream) {
    const float* x       = (const float*)d_in[0];
    const float* kernels = (const float*)d_in[1];
    const float* bias    = (const float*)d_in[2];
    float* out           = (float*)d_out;

    dim3 grid(CN_BATCH / 4);
    dim3 block(256);
    crossnet_kernel<<<grid, block, 0, stream>>>(x, kernels, bias, out);
}

// Round 4
// 25.988 us; speedup vs baseline: 1.1739x; 1.1739x over previous
//
#include <hip/hip_runtime.h>

// CrossNet: x_{l+1} = x0 * (xl . w_l) + xl + b_l, 3 layers, fused.
// BATCH=16384, DIM=1024, LAYER_NUM=3.
// R3: revert nontemporal (R2 post-mortem: x is L3-resident across graph
// replays; NT loads bypassed Infinity Cache and cost +6%). Add 2-rows-per-
// wave ILP: doubles outstanding loads + interleaves the two serial shfl
// reduce chains, and halves kernels/bias traffic (shared k/b registers).

#define CN_BATCH 16384
#define CN_DIM   1024
#define CN_LAYERS 3

typedef float f32x4 __attribute__((ext_vector_type(4)));

__global__ __launch_bounds__(256) void crossnet_kernel(
    const float* __restrict__ x,
    const float* __restrict__ kernels,
    const float* __restrict__ bias,
    float* __restrict__ out)
{
    const int wave = threadIdx.x >> 6;                 // 0..3
    const int lane = threadIdx.x & 63;
    const int pair = (blockIdx.x << 2) + wave;         // wave-pair index
    const int rowA = pair * 2;                         // two adjacent rows per wave
    const int rowB = rowA + 1;

    const float* xrowA = x + (size_t)rowA * CN_DIM;
    const float* xrowB = x + (size_t)rowB * CN_DIM;

    // Lane l covers elements {j*256 + l*4 .. +3}, j=0..3 (coalesced 16B/lane).
    f32x4 x0A[4], xlA[4], x0B[4], xlB[4];
#pragma unroll
    for (int j = 0; j < 4; ++j) {
        x0A[j] = *reinterpret_cast<const f32x4*>(xrowA + j * 256 + lane * 4);
        x0B[j] = *reinterpret_cast<const f32x4*>(xrowB + j * 256 + lane * 4);
    }
#pragma unroll
    for (int j = 0; j < 4; ++j) { xlA[j] = x0A[j]; xlB[j] = x0B[j]; }

#pragma unroll
    for (int i = 0; i < CN_LAYERS; ++i) {
        const float* krow = kernels + i * CN_DIM;
        const float* brow = bias    + i * CN_DIM;

        // Partial dots for both rows over this lane's 16 elements; k shared.
        float pA = 0.0f, pB = 0.0f;
#pragma unroll
        for (int j = 0; j < 4; ++j) {
            f32x4 k = *reinterpret_cast<const f32x4*>(krow + j * 256 + lane * 4);
            pA = fmaf(xlA[j].x, k.x, pA);  pB = fmaf(xlB[j].x, k.x, pB);
            pA = fmaf(xlA[j].y, k.y, pA);  pB = fmaf(xlB[j].y, k.y, pB);
            pA = fmaf(xlA[j].z, k.z, pA);  pB = fmaf(xlB[j].z, k.z, pB);
            pA = fmaf(xlA[j].w, k.w, pA);  pB = fmaf(xlB[j].w, k.w, pB);
        }
        // Two interleaved 64-lane butterflies (independent latency chains).
#pragma unroll
        for (int off = 32; off >= 1; off >>= 1) {
            pA += __shfl_xor(pA, off, 64);
            pB += __shfl_xor(pB, off, 64);
        }
        const float sA = pA, sB = pB;

        // xl = x0 * s + xl + bias_i  (b shared by both rows)
#pragma unroll
        for (int j = 0; j < 4; ++j) {
            f32x4 b = *reinterpret_cast<const f32x4*>(brow + j * 256 + lane * 4);
            xlA[j].x = fmaf(x0A[j].x, sA, xlA[j].x) + b.x;
            xlA[j].y = fmaf(x0A[j].y, sA, xlA[j].y) + b.y;
            xlA[j].z = fmaf(x0A[j].z, sA, xlA[j].z) + b.z;
            xlA[j].w = fmaf(x0A[j].w, sA, xlA[j].w) + b.w;
            xlB[j].x = fmaf(x0B[j].x, sB, xlB[j].x) + b.x;
            xlB[j].y = fmaf(x0B[j].y, sB, xlB[j].y) + b.y;
            xlB[j].z = fmaf(x0B[j].z, sB, xlB[j].z) + b.z;
            xlB[j].w = fmaf(x0B[j].w, sB, xlB[j].w) + b.w;
        }
    }

    float* orowA = out + (size_t)rowA * CN_DIM;
    float* orowB = out + (size_t)rowB * CN_DIM;
#pragma unroll
    for (int j = 0; j < 4; ++j) {
        *reinterpret_cast<f32x4*>(orowA + j * 256 + lane * 4) = xlA[j];
        *reinterpret_cast<f32x4*>(orowB + j * 256 + lane * 4) = xlB[j];
    }
}

extern "C" void kernel_launch(void* const* d_in, const int* in_sizes, int n_in,
                              void* d_out, int out_size, void* d_ws, size_t ws_size,
                              hipStream_t stream) {
    const float* x       = (const float*)d_in[0];
    const float* kernels = (const float*)d_in[1];
    const float* bias    = (const float*)d_in[2];
    float* out           = (float*)d_out;

    // 2 rows per wave, 4 waves per block -> 8 rows per block.
    dim3 grid(CN_BATCH / 8);
    dim3 block(256);
    crossnet_kernel<<<grid, block, 0, stream>>>(x, kernels, bias, out);
}